// Round 1
// baseline (466.372 us; speedup 1.0000x reference)
//
#include <hip/hip_runtime.h>

#define DEV __device__ __forceinline__

typedef unsigned short u16;
typedef short bf16x8 __attribute__((ext_vector_type(8)));
typedef float f32x4 __attribute__((ext_vector_type(4)));

// ---- problem constants (match reference) ----
#define BB    32
#define NOBJ  16
#define NREL  64
#define CCH   1024
#define FHW   50
#define HW    2500      // 50*50
#define NROI  512       // BB*NOBJ
#define MROWS 25088     // NROI*49  (= 196*128)
#define D1    1024
#define D2    512

DEV u16 f2bf(float f) {
  unsigned u = __float_as_uint(f);
  unsigned r = (u + 0x7FFFu + ((u >> 16) & 1u)) >> 16;
  return (u16)r;
}
DEV float bf2f(u16 h) { return __uint_as_float((unsigned)h << 16); }

using gvoid = __attribute__((address_space(1))) const void;
using svoid = __attribute__((address_space(3))) void;
DEV void gl_lds16(const void* g, void* s) {
  __builtin_amdgcn_global_load_lds((gvoid*)g, (svoid*)s, 16, 0, 0);
}

// ---------------- transpose + cast f32 -> bf16 ----------------
// in: (batch, R, C) f32 ; out: (batch, C, R) bf16
__global__ __launch_bounds__(256) void k_transpose_cast(
    const float* __restrict__ in, u16* __restrict__ out, int R, int C) {
  __shared__ float tile[32][33];
  int b = blockIdx.z;
  int c0 = blockIdx.x * 32;
  int r0 = blockIdx.y * 32;
  const float* inb = in + (size_t)b * R * C;
  u16* outb = out + (size_t)b * R * C;
  int tx = threadIdx.x & 31, ty = threadIdx.x >> 5;  // 32 x 8
#pragma unroll
  for (int i = 0; i < 32; i += 8) {
    int r = r0 + ty + i, c = c0 + tx;
    if (r < R && c < C) tile[ty + i][tx] = inb[(size_t)r * C + c];
  }
  __syncthreads();
#pragma unroll
  for (int i = 0; i < 32; i += 8) {
    int c = c0 + ty + i, r = r0 + tx;
    if (c < C && r < R) outb[(size_t)c * R + r] = f2bf(tile[tx][ty + i]);
  }
}

// ---------------- ROI align -> A (MROWS x CCH) bf16 ----------------
DEV void acc4t(const u16* p, float w, float& a0, float& a1, float& a2, float& a3) {
  uint2 v = *reinterpret_cast<const uint2*>(p);
  a0 = fmaf(w, bf2f((u16)(v.x & 0xffffu)), a0);
  a1 = fmaf(w, bf2f((u16)(v.x >> 16)), a1);
  a2 = fmaf(w, bf2f((u16)(v.y & 0xffffu)), a2);
  a3 = fmaf(w, bf2f((u16)(v.y >> 16)), a3);
}

template <bool USET>
__global__ __launch_bounds__(64) void k_roi(
    const u16* __restrict__ fmT, const float* __restrict__ fmap,
    const float* __restrict__ bboxes, const int* __restrict__ pfw,
    const int* __restrict__ pfh, u16* __restrict__ Aout) {
  const int r = blockIdx.x;  // roi index 0..511
  const int b = r >> 4;
  const int t = threadIdx.x;
  const int c0 = (blockIdx.y * 64 + t) * 4;  // 4 channels per thread

  __shared__ int s_lo[2][14], s_hi[2][14];
  __shared__ float s_w0[2][14], s_w1[2][14], s_v[2][14];

  int axis = -1, i = 0;
  if (t < 14) { axis = 0; i = t; }
  else if (t >= 32 && t < 46) { axis = 1; i = t - 32; }
  if (axis >= 0) {
    float fwf = (float)pfw[0], fhf = (float)pfh[0];
    // reference: im_height = frame_width, im_width = frame_height
    float hs = (float)FHW / fwf;
    float wsc = (float)FHW / fhf;
    float v1 = bboxes[r * 4 + (axis == 0 ? 1 : 0)] * (axis == 0 ? hs : wsc);
    float v2 = bboxes[r * 4 + (axis == 0 ? 3 : 2)] * (axis == 0 ? hs : wsc);
    float ext = fmaxf(v2 - v1, 1.0f);
    float g = (float)(i >> 1) + ((i & 1) ? 0.75f : 0.25f);
    float coord = v1 + (ext / 7.0f) * g;
    float valid = (coord >= -1.0f && coord <= 50.0f) ? 1.0f : 0.0f;
    float cc = fmaxf(coord, 0.0f);
    int lo = (int)floorf(cc);
    bool edge = (lo >= FHW - 1);
    lo = min(lo, FHW - 1);
    int hi = min(lo + 1, FHW - 1);
    float l = edge ? 0.0f : (cc - (float)lo);
    s_lo[axis][i] = lo; s_hi[axis][i] = hi;
    s_w0[axis][i] = 1.0f - l; s_w1[axis][i] = l; s_v[axis][i] = valid;
  }
  __syncthreads();

  const u16* bt = fmT + (size_t)b * HW * CCH;
  const float* bf0 = fmap + (size_t)b * CCH * HW;
  const float* bfc = USET ? nullptr : (bf0 + (size_t)c0 * HW);

  for (int bin = 0; bin < 49; ++bin) {
    int py = bin / 7, px = bin % 7;
    float a0 = 0.f, a1 = 0.f, a2 = 0.f, a3 = 0.f;
#pragma unroll
    for (int s = 0; s < 4; ++s) {
      int sy = s >> 1, sx = s & 1;
      int iy = py * 2 + sy, jx = px * 2 + sx;
      int yl = s_lo[0][iy], yh = s_hi[0][iy];
      int xl = s_lo[1][jx], xh = s_hi[1][jx];
      float vv = s_v[0][iy] * s_v[1][jx];
      float wy0 = s_w0[0][iy] * vv, wy1 = s_w1[0][iy] * vv;
      float wx0 = s_w0[1][jx], wx1 = s_w1[1][jx];
      float w00 = wy0 * wx0, w01 = wy0 * wx1, w10 = wy1 * wx0, w11 = wy1 * wx1;
      if (USET) {
        acc4t(bt + (size_t)(yl * FHW + xl) * CCH + c0, w00, a0, a1, a2, a3);
        acc4t(bt + (size_t)(yl * FHW + xh) * CCH + c0, w01, a0, a1, a2, a3);
        acc4t(bt + (size_t)(yh * FHW + xl) * CCH + c0, w10, a0, a1, a2, a3);
        acc4t(bt + (size_t)(yh * FHW + xh) * CCH + c0, w11, a0, a1, a2, a3);
      } else {
        int p00 = yl * FHW + xl, p01 = yl * FHW + xh;
        int p10 = yh * FHW + xl, p11 = yh * FHW + xh;
        a0 += w00 * bfc[0 * HW + p00] + w01 * bfc[0 * HW + p01] + w10 * bfc[0 * HW + p10] + w11 * bfc[0 * HW + p11];
        a1 += w00 * bfc[1 * HW + p00] + w01 * bfc[1 * HW + p01] + w10 * bfc[1 * HW + p10] + w11 * bfc[1 * HW + p11];
        a2 += w00 * bfc[2 * HW + p00] + w01 * bfc[2 * HW + p01] + w10 * bfc[2 * HW + p10] + w11 * bfc[2 * HW + p11];
        a3 += w00 * bfc[3 * HW + p00] + w01 * bfc[3 * HW + p01] + w10 * bfc[3 * HW + p10] + w11 * bfc[3 * HW + p11];
      }
    }
    u16* dst = Aout + (size_t)(r * 49 + bin) * CCH + c0;
    ushort4 o;
    o.x = f2bf(a0 * 0.25f); o.y = f2bf(a1 * 0.25f);
    o.z = f2bf(a2 * 0.25f); o.w = f2bf(a3 * 0.25f);
    *reinterpret_cast<ushort4*>(dst) = o;
  }
}

// ---------------- GEMM: C = relu(A @ B^T' + bias) ----------------
// A: (M,K) bf16 row-major.  Bt: (N,K) bf16 row-major (i.e. B transposed).
// m97 structure: 128x128 tile, BK=32, 4 waves (2x2), 4x4 16x16 frags/wave.
template <int K, int N, int OBF>
__global__ __launch_bounds__(256) void k_gemm(
    const u16* __restrict__ A, const u16* __restrict__ Bt,
    const float* __restrict__ bias, void* __restrict__ Out) {
  __shared__ alignas(16) u16 As[128 * 32];
  __shared__ alignas(16) u16 Bs[128 * 32];
  const int t = threadIdx.x;
  const int lane = t & 63, w = t >> 6;
  const int wr = w >> 1, wc = w & 1;
  const size_t m0 = (size_t)blockIdx.x * 128;
  const int n0 = blockIdx.y * 128;

  f32x4 acc[4][4] = {};

  const int srow = t >> 2;          // staging row 0..63
  const int skc = (t & 3) * 8;      // k-chunk offset (bf16 elems)

  for (int ks = 0; ks < K / 32; ++ks) {
    const int k0 = ks * 32;
    if (ks) __syncthreads();
    // stage A tile [128][32] and B tile [128][32] (both row-major, linear LDS)
    gl_lds16(A + (m0 + srow) * K + k0 + skc, &As[(size_t)t * 8]);
    gl_lds16(A + (m0 + 64 + srow) * K + k0 + skc, &As[(size_t)(t + 256) * 8]);
    gl_lds16(Bt + (size_t)(n0 + srow) * K + k0 + skc, &Bs[(size_t)t * 8]);
    gl_lds16(Bt + (size_t)(n0 + 64 + srow) * K + k0 + skc, &Bs[(size_t)(t + 256) * 8]);
    __syncthreads();

    const int koff = (lane >> 4) * 8;
    bf16x8 av[4], bv[4];
#pragma unroll
    for (int m = 0; m < 4; ++m)
      av[m] = *reinterpret_cast<const bf16x8*>(&As[(wr * 64 + m * 16 + (lane & 15)) * 32 + koff]);
#pragma unroll
    for (int n = 0; n < 4; ++n)
      bv[n] = *reinterpret_cast<const bf16x8*>(&Bs[(wc * 64 + n * 16 + (lane & 15)) * 32 + koff]);
#pragma unroll
    for (int m = 0; m < 4; ++m)
#pragma unroll
      for (int n = 0; n < 4; ++n)
        asm("v_mfma_f32_16x16x32_bf16 %0, %1, %2, %0"
            : "+v"(acc[m][n]) : "v"(av[m]), "v"(bv[n]));
  }
  // MFMA -> VALU read hazard guard (inline asm hides latency from compiler)
  asm volatile("s_nop 7\n\ts_nop 7\n\ts_nop 7" ::);

#pragma unroll
  for (int n = 0; n < 4; ++n) {
    int col = n0 + wc * 64 + n * 16 + (lane & 15);
    float bb = bias[col];
#pragma unroll
    for (int m = 0; m < 4; ++m) {
      size_t row0 = m0 + wr * 64 + m * 16 + (lane >> 4) * 4;
#pragma unroll
      for (int q = 0; q < 4; ++q) {
        float v = fmaxf(acc[m][n][q] + bb, 0.0f);
        if (OBF) ((u16*)Out)[(row0 + q) * N + col] = f2bf(v);
        else     ((float*)Out)[(row0 + q) * N + col] = v;
      }
    }
  }
}

// ---------------- mean over 49 bins ----------------
__global__ __launch_bounds__(256) void k_mean(const float* __restrict__ H2,
                                              float* __restrict__ feat) {
  int r = blockIdx.x;
  for (int c = threadIdx.x; c < D2; c += 256) {
    float s = 0.f;
#pragma unroll
    for (int q = 0; q < 49; ++q) s += H2[((size_t)r * 49 + q) * D2 + c];
    feat[(size_t)r * D2 + c] = s * (1.0f / 49.0f);
  }
}

// ---------------- pair gather ----------------
__global__ __launch_bounds__(256) void k_pairs(
    const float* __restrict__ feat, const int* __restrict__ num_obj,
    const int* __restrict__ pairs, float* __restrict__ out) {
  int r = blockIdx.x;  // 0..2047  (b*64 + rel)
  int b = r >> 6;
  int off = 0;
  for (int i = 0; i < b; ++i) off += num_obj[i];
  int g0 = off + pairs[r * 2 + 0];
  int g1 = off + pairs[r * 2 + 1];
  for (int c = threadIdx.x; c < D2; c += 256) {
    out[(size_t)r * D2 + c] = 0.5f * (feat[(size_t)g0 * D2 + c] + feat[(size_t)g1 * D2 + c]);
  }
}

extern "C" void kernel_launch(void* const* d_in, const int* in_sizes, int n_in,
                              void* d_out, int out_size, void* d_ws, size_t ws_size,
                              hipStream_t stream) {
  const float* fmap = (const float*)d_in[0];
  const float* bboxes = (const float*)d_in[1];
  const int* num_obj = (const int*)d_in[2];
  const int* obj_pairs = (const int*)d_in[3];
  const int* pfw = (const int*)d_in[5];
  const int* pfh = (const int*)d_in[6];
  const float* W1 = (const float*)d_in[7];
  const float* b1 = (const float*)d_in[8];
  const float* W2 = (const float*)d_in[9];
  const float* b2 = (const float*)d_in[10];
  float* out = (float*)d_out;

  const size_t SZ_FMT = (size_t)BB * HW * CCH * 2;   // 163,840,000
  const size_t SZ_A   = (size_t)MROWS * D1 * 2;      // 51,380,224
  const size_t SZ_H1  = (size_t)MROWS * D1 * 2;
  const size_t SZ_W1B = (size_t)D1 * D1 * 2;
  const size_t SZ_W2B = (size_t)D1 * D2 * 2;
  const size_t SZ_FEAT = (size_t)NROI * D2 * 4;

  char* ws = (char*)d_ws;
  const bool fast = ws_size >= SZ_FMT + SZ_A + SZ_H1 + SZ_W1B + SZ_W2B + SZ_FEAT;

  u16 *fmT, *A, *H1, *W1b, *W2b;
  float *H2, *feat;
  if (fast) {
    fmT = (u16*)ws;
    A = (u16*)(ws + SZ_FMT);
    H1 = (u16*)(ws + SZ_FMT + SZ_A);
    W1b = (u16*)(ws + SZ_FMT + SZ_A + SZ_H1);
    W2b = (u16*)(ws + SZ_FMT + SZ_A + SZ_H1 + SZ_W1B);
    feat = (float*)(ws + SZ_FMT + SZ_A + SZ_H1 + SZ_W1B + SZ_W2B);
    H2 = (float*)fmT;  // fmT dead after ROI align
  } else {
    fmT = nullptr;
    A = (u16*)ws;
    H1 = (u16*)(ws + SZ_A);
    W1b = (u16*)(ws + SZ_A + SZ_H1);
    W2b = (u16*)(ws + SZ_A + SZ_H1 + SZ_W1B);
    feat = (float*)(ws + SZ_A + SZ_H1 + SZ_W1B + SZ_W2B);
    H2 = (float*)A;  // A dead after GEMM1
  }

  // weight transposes (K,N)->(N,K) bf16
  k_transpose_cast<<<dim3(32, 32, 1), 256, 0, stream>>>(W1, W1b, D1, D1);
  k_transpose_cast<<<dim3(16, 32, 1), 256, 0, stream>>>(W2, W2b, D1, D2);

  if (fast) {
    // fmap (B,C,HW) -> (B,HW,C) bf16
    k_transpose_cast<<<dim3(79, 32, BB), 256, 0, stream>>>(fmap, fmT, CCH, HW);
    k_roi<true><<<dim3(NROI, 4), 64, 0, stream>>>(fmT, fmap, bboxes, pfw, pfh, A);
  } else {
    k_roi<false><<<dim3(NROI, 4), 64, 0, stream>>>(nullptr, fmap, bboxes, pfw, pfh, A);
  }

  k_gemm<D1, D1, 1><<<dim3(MROWS / 128, D1 / 128), 256, 0, stream>>>(A, W1b, b1, (void*)H1);
  k_gemm<D1, D2, 0><<<dim3(MROWS / 128, D2 / 128), 256, 0, stream>>>(H1, W2b, b2, (void*)H2);
  k_mean<<<NROI, 256, 0, stream>>>(H2, feat);
  k_pairs<<<BB * NREL, 256, 0, stream>>>(feat, num_obj, obj_pairs, out);
}

// Round 2
// 290.984 us; speedup vs baseline: 1.6027x; 1.6027x over previous
//
#include <hip/hip_runtime.h>

#define DEV __device__ __forceinline__

typedef unsigned short u16;
typedef short bf16x8 __attribute__((ext_vector_type(8)));
typedef float f32x4 __attribute__((ext_vector_type(4)));

// ---- problem constants (match reference) ----
#define BB    32
#define NOBJ  16
#define NREL  64
#define CCH   1024
#define FHW   50
#define HW    2500      // 50*50
#define NROI  512       // BB*NOBJ
#define MROWS 25088     // NROI*49  (= 196*128)
#define D1    1024
#define D2    512

DEV u16 f2bf(float f) {
  unsigned u = __float_as_uint(f);
  unsigned r = (u + 0x7FFFu + ((u >> 16) & 1u)) >> 16;
  return (u16)r;
}
DEV float bf2f(u16 h) { return __uint_as_float((unsigned)h << 16); }
DEV unsigned pk(float lo, float hi) { return (unsigned)f2bf(lo) | ((unsigned)f2bf(hi) << 16); }

using gvoid = __attribute__((address_space(1))) const void;
using svoid = __attribute__((address_space(3))) void;
DEV void gl_lds16(const void* g, void* s) {
  __builtin_amdgcn_global_load_lds((gvoid*)g, (svoid*)s, 16, 0, 0);
}

// ---------------- transpose + cast f32 -> bf16 ----------------
// in: (batch, R, C) f32 ; out: (batch, C, R) bf16.  Requires R % 64 == 0.
__global__ __launch_bounds__(256) void k_transpose_cast(
    const float* __restrict__ in, u16* __restrict__ out, int R, int C) {
  __shared__ float tile[64][65];
  const int b = blockIdx.z;
  const int c0 = blockIdx.x * 64;
  const int r0 = blockIdx.y * 64;
  const float* inb = in + (size_t)b * R * C;
  u16* outb = out + (size_t)b * R * C;
  const int t = threadIdx.x;

  // load phase: 16 rows x 16 float4-cols per iter, 4 iters
  {
    const int rr = t >> 4;
    const int cq = (t & 15) * 4;
#pragma unroll
    for (int it = 0; it < 4; ++it) {
      int rl = rr + it * 16;
      int r = r0 + rl;
      int c = c0 + cq;
      if (c + 3 < C) {
        float4 v = *reinterpret_cast<const float4*>(&inb[(size_t)r * C + c]);
        tile[rl][cq + 0] = v.x; tile[rl][cq + 1] = v.y;
        tile[rl][cq + 2] = v.z; tile[rl][cq + 3] = v.w;
      } else {
#pragma unroll
        for (int j = 0; j < 4; ++j)
          tile[rl][cq + j] = (c + j < C) ? inb[(size_t)r * C + c + j] : 0.f;
      }
    }
  }
  __syncthreads();
  // store phase: lanes t: c = t>>2, rchunk = (t&3)*8; two halves (r +0, +32)
  {
    const int c = t >> 2;
    const int rch = (t & 3) * 8;
    if (c0 + c < C) {
#pragma unroll
      for (int half = 0; half < 2; ++half) {
        int rb = rch + half * 32;
        uint4 o;
        o.x = pk(tile[rb + 0][c], tile[rb + 1][c]);
        o.y = pk(tile[rb + 2][c], tile[rb + 3][c]);
        o.z = pk(tile[rb + 4][c], tile[rb + 5][c]);
        o.w = pk(tile[rb + 6][c], tile[rb + 7][c]);
        *reinterpret_cast<uint4*>(&outb[(size_t)(c0 + c) * R + r0 + rb]) = o;
      }
    }
  }
}

// ---------------- ROI align (fast path, fmT gather) ----------------
DEV void acc8(const u16* p, float w, float* a) {
  uint4 v = *reinterpret_cast<const uint4*>(p);
  a[0] = fmaf(w, bf2f((u16)(v.x & 0xffffu)), a[0]);
  a[1] = fmaf(w, bf2f((u16)(v.x >> 16)), a[1]);
  a[2] = fmaf(w, bf2f((u16)(v.y & 0xffffu)), a[2]);
  a[3] = fmaf(w, bf2f((u16)(v.y >> 16)), a[3]);
  a[4] = fmaf(w, bf2f((u16)(v.z & 0xffffu)), a[4]);
  a[5] = fmaf(w, bf2f((u16)(v.z >> 16)), a[5]);
  a[6] = fmaf(w, bf2f((u16)(v.w & 0xffffu)), a[6]);
  a[7] = fmaf(w, bf2f((u16)(v.w >> 16)), a[7]);
}

__global__ __launch_bounds__(128) void k_roi_fast(
    const u16* __restrict__ fmT, const float* __restrict__ bboxes,
    const int* __restrict__ pfw, const int* __restrict__ pfh,
    u16* __restrict__ Aout) {
  const int r = blockIdx.x;   // roi 0..511
  const int py = blockIdx.y;  // bin row 0..6
  const int b = r >> 4;
  const int t = threadIdx.x;
  const int c0 = t * 8;

  __shared__ int s_lo[2][14], s_hi[2][14];
  __shared__ float s_w0[2][14], s_w1[2][14], s_v[2][14];

  int axis = -1, i = 0;
  if (t < 14) { axis = 0; i = t; }
  else if (t >= 64 && t < 78) { axis = 1; i = t - 64; }
  if (axis >= 0) {
    float fwf = (float)pfw[0], fhf = (float)pfh[0];
    // reference: im_height = frame_width, im_width = frame_height
    float hs = (float)FHW / fwf;
    float wsc = (float)FHW / fhf;
    float v1 = bboxes[r * 4 + (axis == 0 ? 1 : 0)] * (axis == 0 ? hs : wsc);
    float v2 = bboxes[r * 4 + (axis == 0 ? 3 : 2)] * (axis == 0 ? hs : wsc);
    float ext = fmaxf(v2 - v1, 1.0f);
    float g = (float)(i >> 1) + ((i & 1) ? 0.75f : 0.25f);
    float coord = v1 + (ext / 7.0f) * g;
    float valid = (coord >= -1.0f && coord <= 50.0f) ? 1.0f : 0.0f;
    float cc = fmaxf(coord, 0.0f);
    int lo = (int)floorf(cc);
    bool edge = (lo >= FHW - 1);
    lo = min(lo, FHW - 1);
    int hi = min(lo + 1, FHW - 1);
    float l = edge ? 0.0f : (cc - (float)lo);
    s_lo[axis][i] = lo; s_hi[axis][i] = hi;
    s_w0[axis][i] = 1.0f - l; s_w1[axis][i] = l; s_v[axis][i] = valid;
  }
  __syncthreads();

  const u16* bt = fmT + (size_t)b * HW * CCH + c0;

  for (int px = 0; px < 7; ++px) {
    float a[8] = {};
#pragma unroll
    for (int s = 0; s < 4; ++s) {
      int sy = s >> 1, sx = s & 1;
      int iy = py * 2 + sy, jx = px * 2 + sx;
      int yl = s_lo[0][iy], yh = s_hi[0][iy];
      int xl = s_lo[1][jx], xh = s_hi[1][jx];
      float vv = s_v[0][iy] * s_v[1][jx];
      float wy0 = s_w0[0][iy] * vv, wy1 = s_w1[0][iy] * vv;
      float wx0 = s_w0[1][jx], wx1 = s_w1[1][jx];
      acc8(bt + (size_t)(yl * FHW + xl) * CCH, wy0 * wx0, a);
      acc8(bt + (size_t)(yl * FHW + xh) * CCH, wy0 * wx1, a);
      acc8(bt + (size_t)(yh * FHW + xl) * CCH, wy1 * wx0, a);
      acc8(bt + (size_t)(yh * FHW + xh) * CCH, wy1 * wx1, a);
    }
    u16* dst = Aout + (size_t)(r * 49 + py * 7 + px) * CCH + c0;
    uint4 o;
    o.x = pk(a[0] * 0.25f, a[1] * 0.25f);
    o.y = pk(a[2] * 0.25f, a[3] * 0.25f);
    o.z = pk(a[4] * 0.25f, a[5] * 0.25f);
    o.w = pk(a[6] * 0.25f, a[7] * 0.25f);
    *reinterpret_cast<uint4*>(dst) = o;
  }
}

// ---------------- ROI align (fallback: gather from f32 fmap) ----------------
__global__ __launch_bounds__(64) void k_roi_slow(
    const float* __restrict__ fmap, const float* __restrict__ bboxes,
    const int* __restrict__ pfw, const int* __restrict__ pfh,
    u16* __restrict__ Aout) {
  const int r = blockIdx.x;
  const int b = r >> 4;
  const int t = threadIdx.x;
  const int c0 = (blockIdx.y * 64 + t) * 4;

  __shared__ int s_lo[2][14], s_hi[2][14];
  __shared__ float s_w0[2][14], s_w1[2][14], s_v[2][14];

  int axis = -1, i = 0;
  if (t < 14) { axis = 0; i = t; }
  else if (t >= 32 && t < 46) { axis = 1; i = t - 32; }
  if (axis >= 0) {
    float fwf = (float)pfw[0], fhf = (float)pfh[0];
    float hs = (float)FHW / fwf;
    float wsc = (float)FHW / fhf;
    float v1 = bboxes[r * 4 + (axis == 0 ? 1 : 0)] * (axis == 0 ? hs : wsc);
    float v2 = bboxes[r * 4 + (axis == 0 ? 3 : 2)] * (axis == 0 ? hs : wsc);
    float ext = fmaxf(v2 - v1, 1.0f);
    float g = (float)(i >> 1) + ((i & 1) ? 0.75f : 0.25f);
    float coord = v1 + (ext / 7.0f) * g;
    float valid = (coord >= -1.0f && coord <= 50.0f) ? 1.0f : 0.0f;
    float cc = fmaxf(coord, 0.0f);
    int lo = (int)floorf(cc);
    bool edge = (lo >= FHW - 1);
    lo = min(lo, FHW - 1);
    int hi = min(lo + 1, FHW - 1);
    float l = edge ? 0.0f : (cc - (float)lo);
    s_lo[axis][i] = lo; s_hi[axis][i] = hi;
    s_w0[axis][i] = 1.0f - l; s_w1[axis][i] = l; s_v[axis][i] = valid;
  }
  __syncthreads();

  const float* bfc = fmap + (size_t)b * CCH * HW + (size_t)c0 * HW;

  for (int bin = 0; bin < 49; ++bin) {
    int py = bin / 7, px = bin % 7;
    float a0 = 0.f, a1 = 0.f, a2 = 0.f, a3 = 0.f;
#pragma unroll
    for (int s = 0; s < 4; ++s) {
      int sy = s >> 1, sx = s & 1;
      int iy = py * 2 + sy, jx = px * 2 + sx;
      int yl = s_lo[0][iy], yh = s_hi[0][iy];
      int xl = s_lo[1][jx], xh = s_hi[1][jx];
      float vv = s_v[0][iy] * s_v[1][jx];
      float wy0 = s_w0[0][iy] * vv, wy1 = s_w1[0][iy] * vv;
      float wx0 = s_w0[1][jx], wx1 = s_w1[1][jx];
      float w00 = wy0 * wx0, w01 = wy0 * wx1, w10 = wy1 * wx0, w11 = wy1 * wx1;
      int p00 = yl * FHW + xl, p01 = yl * FHW + xh;
      int p10 = yh * FHW + xl, p11 = yh * FHW + xh;
      a0 += w00 * bfc[0 * HW + p00] + w01 * bfc[0 * HW + p01] + w10 * bfc[0 * HW + p10] + w11 * bfc[0 * HW + p11];
      a1 += w00 * bfc[1 * HW + p00] + w01 * bfc[1 * HW + p01] + w10 * bfc[1 * HW + p10] + w11 * bfc[1 * HW + p11];
      a2 += w00 * bfc[2 * HW + p00] + w01 * bfc[2 * HW + p01] + w10 * bfc[2 * HW + p10] + w11 * bfc[2 * HW + p11];
      a3 += w00 * bfc[3 * HW + p00] + w01 * bfc[3 * HW + p01] + w10 * bfc[3 * HW + p10] + w11 * bfc[3 * HW + p11];
    }
    u16* dst = Aout + (size_t)(r * 49 + bin) * CCH + c0;
    ushort4 o;
    o.x = f2bf(a0 * 0.25f); o.y = f2bf(a1 * 0.25f);
    o.z = f2bf(a2 * 0.25f); o.w = f2bf(a3 * 0.25f);
    *reinterpret_cast<ushort4*>(dst) = o;
  }
}

// ---------------- GEMM: Out = relu(A @ Bt^T + bias) ----------------
// A: (M,K) bf16 row-major.  Bt: (N,K) bf16 row-major.
// m97 structure: 128x128 tile, BK=32, 4 waves (2x2), 4x4 16x16 frags/wave.
// 1D grid, XCD-chunked swizzle, n-tile fastest (A-panel reuse within XCD L2).
template <int K, int N, int OBF>
__global__ __launch_bounds__(256) void k_gemm(
    const u16* __restrict__ A, const u16* __restrict__ Bt,
    const float* __restrict__ bias, void* __restrict__ Out) {
  __shared__ alignas(16) u16 As[128 * 32];
  __shared__ alignas(16) u16 Bs[128 * 32];
  const int t = threadIdx.x;
  const int lane = t & 63, w = t >> 6;
  const int wr = w >> 1, wc = w & 1;

  const int NT = N / 128;
  const int bid = blockIdx.x;
  const int chunk = (int)(gridDim.x >> 3);  // gridDim.x % 8 == 0
  const int swz = (bid & 7) * chunk + (bid >> 3);
  const size_t m0 = (size_t)(swz / NT) * 128;
  const int n0 = (swz % NT) * 128;

  f32x4 acc[4][4] = {};

  const int srow = t >> 2;          // staging row 0..63
  const int skc = (t & 3) * 8;      // k-chunk offset (bf16 elems)

  for (int ks = 0; ks < K / 32; ++ks) {
    const int k0 = ks * 32;
    if (ks) __syncthreads();
    gl_lds16(A + (m0 + srow) * K + k0 + skc, &As[(size_t)t * 8]);
    gl_lds16(A + (m0 + 64 + srow) * K + k0 + skc, &As[(size_t)(t + 256) * 8]);
    gl_lds16(Bt + (size_t)(n0 + srow) * K + k0 + skc, &Bs[(size_t)t * 8]);
    gl_lds16(Bt + (size_t)(n0 + 64 + srow) * K + k0 + skc, &Bs[(size_t)(t + 256) * 8]);
    __syncthreads();

    const int koff = (lane >> 4) * 8;
    bf16x8 av[4], bv[4];
#pragma unroll
    for (int m = 0; m < 4; ++m)
      av[m] = *reinterpret_cast<const bf16x8*>(&As[(wr * 64 + m * 16 + (lane & 15)) * 32 + koff]);
#pragma unroll
    for (int n = 0; n < 4; ++n)
      bv[n] = *reinterpret_cast<const bf16x8*>(&Bs[(wc * 64 + n * 16 + (lane & 15)) * 32 + koff]);
#pragma unroll
    for (int m = 0; m < 4; ++m)
#pragma unroll
      for (int n = 0; n < 4; ++n)
        asm("v_mfma_f32_16x16x32_bf16 %0, %1, %2, %0"
            : "+v"(acc[m][n]) : "v"(av[m]), "v"(bv[n]));
  }
  // MFMA -> VALU read hazard guard (inline asm hides latency from compiler)
  asm volatile("s_nop 7\n\ts_nop 7\n\ts_nop 7" ::);

#pragma unroll
  for (int n = 0; n < 4; ++n) {
    int col = n0 + wc * 64 + n * 16 + (lane & 15);
    float bb = bias[col];
#pragma unroll
    for (int m = 0; m < 4; ++m) {
      size_t row0 = m0 + wr * 64 + m * 16 + (lane >> 4) * 4;
#pragma unroll
      for (int qq = 0; qq < 4; ++qq) {
        float v = fmaxf(acc[m][n][qq] + bb, 0.0f);
        if (OBF) ((u16*)Out)[(row0 + qq) * N + col] = f2bf(v);
        else     ((float*)Out)[(row0 + qq) * N + col] = v;
      }
    }
  }
}

// ---------------- mean over 49 bins (bf16 input) ----------------
__global__ __launch_bounds__(256) void k_mean(const u16* __restrict__ H2,
                                              float* __restrict__ feat) {
  const int r = blockIdx.x;
  const int c = threadIdx.x * 2;
  float s0 = 0.f, s1 = 0.f;
#pragma unroll
  for (int qq = 0; qq < 49; ++qq) {
    unsigned v = *reinterpret_cast<const unsigned*>(&H2[((size_t)r * 49 + qq) * D2 + c]);
    s0 += bf2f((u16)(v & 0xffffu));
    s1 += bf2f((u16)(v >> 16));
  }
  feat[(size_t)r * D2 + c] = s0 * (1.0f / 49.0f);
  feat[(size_t)r * D2 + c + 1] = s1 * (1.0f / 49.0f);
}

// ---------------- pair gather ----------------
__global__ __launch_bounds__(256) void k_pairs(
    const float* __restrict__ feat, const int* __restrict__ num_obj,
    const int* __restrict__ pairs, float* __restrict__ out) {
  int r = blockIdx.x;  // 0..2047  (b*64 + rel)
  int b = r >> 6;
  int off = 0;
  for (int i = 0; i < b; ++i) off += num_obj[i];
  int g0 = off + pairs[r * 2 + 0];
  int g1 = off + pairs[r * 2 + 1];
  for (int c = threadIdx.x; c < D2; c += 256) {
    out[(size_t)r * D2 + c] = 0.5f * (feat[(size_t)g0 * D2 + c] + feat[(size_t)g1 * D2 + c]);
  }
}

extern "C" void kernel_launch(void* const* d_in, const int* in_sizes, int n_in,
                              void* d_out, int out_size, void* d_ws, size_t ws_size,
                              hipStream_t stream) {
  const float* fmap = (const float*)d_in[0];
  const float* bboxes = (const float*)d_in[1];
  const int* num_obj = (const int*)d_in[2];
  const int* obj_pairs = (const int*)d_in[3];
  const int* pfw = (const int*)d_in[5];
  const int* pfh = (const int*)d_in[6];
  const float* W1 = (const float*)d_in[7];
  const float* b1 = (const float*)d_in[8];
  const float* W2 = (const float*)d_in[9];
  const float* b2 = (const float*)d_in[10];
  float* out = (float*)d_out;

  const size_t SZ_FMT = (size_t)BB * HW * CCH * 2;   // 163,840,000
  const size_t SZ_A   = (size_t)MROWS * D1 * 2;      // 51,380,224
  const size_t SZ_H1  = (size_t)MROWS * D1 * 2;
  const size_t SZ_W1B = (size_t)D1 * D1 * 2;
  const size_t SZ_W2B = (size_t)D1 * D2 * 2;
  const size_t SZ_FEAT = (size_t)NROI * D2 * 4;

  char* ws = (char*)d_ws;
  const bool fast = ws_size >= SZ_FMT + SZ_A + SZ_H1 + SZ_W1B + SZ_W2B + SZ_FEAT;

  u16 *fmT, *A, *H1, *W1b, *W2b, *H2b;
  float *feat;
  if (fast) {
    fmT = (u16*)ws;
    A = (u16*)(ws + SZ_FMT);
    H1 = (u16*)(ws + SZ_FMT + SZ_A);
    W1b = (u16*)(ws + SZ_FMT + SZ_A + SZ_H1);
    W2b = (u16*)(ws + SZ_FMT + SZ_A + SZ_H1 + SZ_W1B);
    feat = (float*)(ws + SZ_FMT + SZ_A + SZ_H1 + SZ_W1B + SZ_W2B);
    H2b = fmT;  // fmT dead after ROI align; H2 = 25.7 MB << 163.8 MB
  } else {
    fmT = nullptr;
    A = (u16*)ws;
    H1 = (u16*)(ws + SZ_A);
    W1b = (u16*)(ws + SZ_A + SZ_H1);
    W2b = (u16*)(ws + SZ_A + SZ_H1 + SZ_W1B);
    feat = (float*)(ws + SZ_A + SZ_H1 + SZ_W1B + SZ_W2B);
    H2b = A;  // A dead after GEMM1
  }

  // weight transposes (K,N)->(N,K) bf16   (R = D1 = 1024, %64==0)
  k_transpose_cast<<<dim3(16, 16, 1), 256, 0, stream>>>(W1, W1b, D1, D1);
  k_transpose_cast<<<dim3(8, 16, 1), 256, 0, stream>>>(W2, W2b, D1, D2);

  if (fast) {
    // fmap (B, C=1024, HW=2500) -> (B, HW, C) bf16
    k_transpose_cast<<<dim3(40, 16, BB), 256, 0, stream>>>(fmap, fmT, CCH, HW);
    k_roi_fast<<<dim3(NROI, 7), 128, 0, stream>>>(fmT, bboxes, pfw, pfh, A);
  } else {
    k_roi_slow<<<dim3(NROI, 4), 64, 0, stream>>>(fmap, bboxes, pfw, pfh, A);
  }

  k_gemm<D1, D1, 1><<<(MROWS / 128) * (D1 / 128), 256, 0, stream>>>(A, W1b, b1, (void*)H1);
  k_gemm<D1, D2, 1><<<(MROWS / 128) * (D2 / 128), 256, 0, stream>>>(H1, W2b, b2, (void*)H2b);
  k_mean<<<NROI, 256, 0, stream>>>(H2b, feat);
  k_pairs<<<BB * NREL, 256, 0, stream>>>(feat, num_obj, obj_pairs, out);
}